// Round 5
// baseline (213.584 us; speedup 1.0000x reference)
//
#include <hip/hip_runtime.h>

#define BB 4
#define NN 10000
#define EE 200000
#define DD 32
#define ND ((size_t)NN * DD)
#define CAP 64   // max in-degree bucketed; Poisson(20) => P(deg>64) ~ 1e-15/node

__device__ __forceinline__ float fast_tanh(float v) {
    float a = fabsf(v);
    float e = __expf(2.0f * a);            // e^{2|v|}; overflows to +inf for big a -> r = 1
    float r = 1.0f - 2.0f / (e + 1.0f);
    return copysignf(r, v);
}

__device__ __forceinline__ float bcast(float v, int lane) {
    return __int_as_float(__builtin_amdgcn_readlane(__float_as_int(v), lane));
}

// Pass 1: bucket edges by dst. cur[] must be zeroed first.
__global__ __launch_bounds__(256) void scatter_kernel(
    const int* __restrict__ eidx, int* __restrict__ cur, int* __restrict__ bucket)
{
    int t = blockIdx.x * 256 + threadIdx.x;
    if (t >= EE) return;
    int dstn = eidx[EE + t];
    int pos = atomicAdd(&cur[dstn], 1);
    if (pos < CAP) bucket[dstn * CAP + pos] = t;
}

// Pass 2: one wave per node. Walk incoming edges, accumulate post-tanh sums in
// registers, then agg/state/batch-norm all within the wave. Zero float atomics.
// lane l: d = l&31 (column), p = l>>5 selects batch pair {2p, 2p+1}.
__global__ __launch_bounds__(256) void fused_node_kernel(
    const float* __restrict__ x,        // (B,N,D)
    const int*   __restrict__ eidx,     // (2,E)
    const float* __restrict__ weight,   // (E,D,D)
    const float* __restrict__ bias,     // (E,D)
    const float* __restrict__ state_w,  // (D,1)
    const float* __restrict__ state_b,  // (1)
    const float* __restrict__ bn_gamma, // (N)
    const float* __restrict__ bn_beta,  // (N)
    const int*   __restrict__ cur,      // (N) in-degree
    const int*   __restrict__ bucket,   // (N,CAP) edge ids
    float* __restrict__ out_state,      // (B,N)
    float* __restrict__ out_bn)         // (B,N,D)
{
    int wid = threadIdx.x >> 6;
    int n = blockIdx.x * 4 + wid;
    if (n >= NN) return;
    int lane = threadIdx.x & 63;
    int d = lane & 31;
    bool p = lane >= 32;

    int deg = __builtin_amdgcn_readfirstlane(cur[n]);
    int m = deg < CAP ? deg : CAP;

    float sum0 = 0.f, sum1 = 0.f;       // post-tanh sums for batches 2p, 2p+1
    for (int j = 0; j < m; ++j) {
        int e   = __builtin_amdgcn_readfirstlane(bucket[n * CAP + j]);
        int src = __builtin_amdgcn_readfirstlane(eidx[e]);

        size_t xoff = (size_t)src * DD + d;
        float xr0 = x[xoff];
        float xr1 = x[xoff + ND];
        float xr2 = x[xoff + 2 * ND];
        float xr3 = x[xoff + 3 * ND];

        const float* __restrict__ W = weight + (size_t)e * (DD * DD);
        float a0 = 0.f, a1 = 0.f, a2 = 0.f, a3 = 0.f;
#pragma unroll
        for (int k = 0; k < DD; ++k) {
            float w = W[k * DD + d];          // 128B coalesced row (R4's proven pattern)
            a0 = fmaf(bcast(xr0, k), w, a0);  // v_readlane -> SGPR operand, no DS pipe
            a1 = fmaf(bcast(xr1, k), w, a1);
            a2 = fmaf(bcast(xr2, k), w, a2);
            a3 = fmaf(bcast(xr3, k), w, a3);
        }
        float bv = bias[(size_t)e * DD + d];
        float accA = p ? a2 : a0;             // this half-wave's batch pair
        float accB = p ? a3 : a1;
        sum0 += fast_tanh(accA + bv);
        sum1 += fast_tanh(accB + bv);
    }

    float inv  = 1.0f / fmaxf((float)deg, 1.0f);
    float agg0 = sum0 * inv;                  // agg[2p]  [.,n,d]
    float agg1 = sum1 * inv;                  // agg[2p+1][.,n,d]

    // state: reduce agg*state_w over d within each half-wave
    float sw = state_w[d];
    float s0 = agg0 * sw, s1 = agg1 * sw;
#pragma unroll
    for (int mm = 16; mm >= 1; mm >>= 1) {
        s0 += __shfl_xor(s0, mm, 32);
        s1 += __shfl_xor(s1, mm, 32);
    }
    if (d == 0) {
        float sb = state_b[0];
        int b0 = p ? 2 : 0;
        out_state[(size_t)b0 * NN + n]       = s0 + sb;
        out_state[(size_t)(b0 + 1) * NN + n] = s1 + sb;
    }

    // batch-norm stats over (B,D) = 128 values (2 per lane)
    float sum = agg0 + agg1;
    float sq  = agg0 * agg0 + agg1 * agg1;
#pragma unroll
    for (int mm = 32; mm >= 1; mm >>= 1) {
        sum += __shfl_xor(sum, mm, 64);
        sq  += __shfl_xor(sq,  mm, 64);
    }
    float mean  = sum * (1.0f / 128.0f);
    float var   = sq  * (1.0f / 128.0f) - mean * mean;
    float scale = rsqrtf(var + 1e-5f);
    float g = bn_gamma[n], be = bn_beta[n];

    size_t base = (size_t)(p ? 2 : 0) * ND + (size_t)n * DD + d;
    out_bn[base]      = (agg0 - mean) * scale * g + be;
    out_bn[base + ND] = (agg1 - mean) * scale * g + be;
}

extern "C" void kernel_launch(void* const* d_in, const int* in_sizes, int n_in,
                              void* d_out, int out_size, void* d_ws, size_t ws_size,
                              hipStream_t stream) {
    const float* x        = (const float*)d_in[0];
    const int*   eidx     = (const int*)  d_in[1];
    const float* weight   = (const float*)d_in[2];
    const float* bias     = (const float*)d_in[3];
    const float* state_w  = (const float*)d_in[4];
    const float* state_b  = (const float*)d_in[5];
    const float* bn_gamma = (const float*)d_in[6];
    const float* bn_beta  = (const float*)d_in[7];

    int* cur    = (int*)d_ws;            // N counters
    int* bucket = cur + NN;              // N*CAP edge ids (2.56 MB)
    hipMemsetAsync(cur, 0, NN * sizeof(int), stream);

    float* out_state = (float*)d_out;                 // B*N
    float* out_bn    = out_state + (size_t)BB * NN;   // B*N*D

    scatter_kernel<<<(EE + 255) / 256, 256, 0, stream>>>(eidx, cur, bucket);
    fused_node_kernel<<<NN / 4, 256, 0, stream>>>(
        x, eidx, weight, bias, state_w, state_b, bn_gamma, bn_beta,
        cur, bucket, out_state, out_bn);
}

// Round 7
// 151.301 us; speedup vs baseline: 1.4116x; 1.4116x over previous
//
#include <hip/hip_runtime.h>
#include <hip/hip_fp16.h>

#define BB 4
#define NN 10000
#define EE 200000
#define DD 32
#define ND ((size_t)NN * DD)

__device__ __forceinline__ float fast_tanh(float v) {
    float a = fabsf(v);
    float e = __expf(2.0f * a);            // e^{2|v|}; overflows to +inf for big a -> r = 1
    float r = 1.0f - 2.0f / (e + 1.0f);
    return copysignf(r, v);
}

__device__ __forceinline__ float bcast(float v, int lane) {
    return __int_as_float(__builtin_amdgcn_readlane(__float_as_int(v), lane));
}

// HW packed-f16 atomic add (gfx90a+): one 4B RMW covering two batches.
__device__ __forceinline__ void atomic_pk_add_f16(__half2* addr, __half2 val) {
    unsigned int v = *reinterpret_cast<unsigned int*>(&val);
    asm volatile("global_atomic_pk_add_f16 %0, %1, off"
                 :: "v"(addr), "v"(v) : "memory");
}

// One wave per edge. R4 compute structure (readlane broadcast, zero DS ops).
// vs R4: (1) sums is (N,D,2) half2, ONE packed-f16 atomic per lane
// (64 atomic lane-ops/edge instead of 128 f32); (2) x fetched by ONE dwordx2
// instruction: lane l holds x[l>>4][src][2*(l&15)+{0,1}]; (3) W/bias nontemporal.
__global__ __launch_bounds__(256) void edge_kernel(
    const float* __restrict__ x,        // (B,N,D)
    const int*   __restrict__ eidx,     // (2,E)
    const float* __restrict__ weight,   // (E,D,D)
    const float* __restrict__ bias,     // (E,D)
    __half2* __restrict__ sums_h,       // (N,D,2): [n][d][p] = batches {2p,2p+1}
    float* __restrict__ cnt)            // (N)
{
    int wid = __builtin_amdgcn_readfirstlane((int)(threadIdx.x >> 6));
    int e = blockIdx.x * 4 + wid;
    if (e >= EE) return;
    int lane = threadIdx.x & 63;
    int d = lane & 31;
    bool p = lane >= 32;                // batch pair {2p, 2p+1}

    int src = __builtin_amdgcn_readfirstlane(eidx[e]);
    int dst = __builtin_amdgcn_readfirstlane(eidx[EE + e]);

    // single 8B/lane load covers all of x[0..3][src][0..31] (512B, no duplication)
    int xb = lane >> 4;                 // batch this lane carries
    int xm = lane & 15;                 // element pair
    float2 xv = *(const float2*)(x + (size_t)xb * ND + (size_t)src * DD + 2 * xm);
    float xlo = xv.x, xhi = xv.y;

    const float* __restrict__ W = weight + (size_t)e * (DD * DD);
    float acc0 = 0.f, acc1 = 0.f, acc2 = 0.f, acc3 = 0.f;
#pragma unroll
    for (int k = 0; k < DD; ++k) {
        float w = __builtin_nontemporal_load(&W[k * DD + d]);
        // x[b][k] lives in lane (b<<4)|(k>>1), component k&1  (all static)
        float x0, x1, x2, x3;
        if (k & 1) {
            x0 = bcast(xhi, (k >> 1));
            x1 = bcast(xhi, 16 + (k >> 1));
            x2 = bcast(xhi, 32 + (k >> 1));
            x3 = bcast(xhi, 48 + (k >> 1));
        } else {
            x0 = bcast(xlo, (k >> 1));
            x1 = bcast(xlo, 16 + (k >> 1));
            x2 = bcast(xlo, 32 + (k >> 1));
            x3 = bcast(xlo, 48 + (k >> 1));
        }
        acc0 = fmaf(x0, w, acc0);
        acc1 = fmaf(x1, w, acc1);
        acc2 = fmaf(x2, w, acc2);
        acc3 = fmaf(x3, w, acc3);
    }
    float bv = __builtin_nontemporal_load(&bias[(size_t)e * DD + d]);
    float aA = p ? acc2 : acc0;         // batch 2p
    float aB = p ? acc3 : acc1;         // batch 2p+1
    float o0 = fast_tanh(aA + bv);
    float o1 = fast_tanh(aB + bv);

    // one packed f16 atomic per lane
    __half2 hv = __floats2half2_rn(o0, o1);
    atomic_pk_add_f16(&sums_h[((size_t)dst * DD + d) * 2 + (p ? 1 : 0)], hv);
    if (lane == 0) atomicAdd(&cnt[dst], 1.0f);
}

// One wave per node. lane l: d = l&31, p = l>>5 -> batches {2p, 2p+1}.
__global__ __launch_bounds__(256) void node_kernel(
    const __half2* __restrict__ sums_h, // (N,D,2)
    const float* __restrict__ cnt,      // (N)
    const float* __restrict__ state_w,  // (D,1)
    const float* __restrict__ state_b,  // (1)
    const float* __restrict__ bn_gamma, // (N)
    const float* __restrict__ bn_beta,  // (N)
    float* __restrict__ out_state,      // (B,N)
    float* __restrict__ out_bn)         // (B,N,D)
{
    int gid = blockIdx.x * blockDim.x + threadIdx.x;
    int n = gid >> 6;
    if (n >= NN) return;
    int lane = gid & 63;
    int d = lane & 31;
    bool p = lane >= 32;

    float inv = 1.0f / fmaxf(cnt[n], 1.0f);
    __half2 hv = sums_h[((size_t)n * DD + d) * 2 + (p ? 1 : 0)];
    float v0 = __half2float(hv.x) * inv;   // agg[2p]  [n][d]
    float v1 = __half2float(hv.y) * inv;   // agg[2p+1][n][d]

    // state: reduce v*state_w over d within each half-wave
    float sw = state_w[d];
    float s0 = v0 * sw, s1 = v1 * sw;
#pragma unroll
    for (int m = 16; m >= 1; m >>= 1) {
        s0 += __shfl_xor(s0, m, 32);
        s1 += __shfl_xor(s1, m, 32);
    }
    if (d == 0) {
        float sb = state_b[0];
        int b0 = p ? 2 : 0;
        out_state[(size_t)b0 * NN + n]       = s0 + sb;
        out_state[(size_t)(b0 + 1) * NN + n] = s1 + sb;
    }

    // mean/var over all B*D = 128 values (2 per lane)
    float sum = v0 + v1;
    float sq  = v0 * v0 + v1 * v1;
#pragma unroll
    for (int m = 32; m >= 1; m >>= 1) {
        sum += __shfl_xor(sum, m, 64);
        sq  += __shfl_xor(sq,  m, 64);
    }
    float mean  = sum * (1.0f / 128.0f);
    float var   = sq  * (1.0f / 128.0f) - mean * mean;
    float scale = rsqrtf(var + 1e-5f);
    float g = bn_gamma[n], be = bn_beta[n];

    size_t base = (size_t)(p ? 2 : 0) * ND + (size_t)n * DD + d;
    out_bn[base]      = (v0 - mean) * scale * g + be;
    out_bn[base + ND] = (v1 - mean) * scale * g + be;
}

extern "C" void kernel_launch(void* const* d_in, const int* in_sizes, int n_in,
                              void* d_out, int out_size, void* d_ws, size_t ws_size,
                              hipStream_t stream) {
    const float* x        = (const float*)d_in[0];
    const int*   eidx     = (const int*)  d_in[1];
    const float* weight   = (const float*)d_in[2];
    const float* bias     = (const float*)d_in[3];
    const float* state_w  = (const float*)d_in[4];
    const float* state_b  = (const float*)d_in[5];
    const float* bn_gamma = (const float*)d_in[6];
    const float* bn_beta  = (const float*)d_in[7];

    __half2* sums_h = (__half2*)d_ws;                     // N*D*2 half2 = 2.56 MB
    float*   cnt    = (float*)((char*)d_ws + (size_t)NN * DD * 2 * sizeof(__half2));
    size_t zero_bytes = (size_t)NN * DD * 2 * sizeof(__half2) + NN * sizeof(float);
    (void)hipMemsetAsync(d_ws, 0, zero_bytes, stream);

    float* out_state = (float*)d_out;                 // B*N
    float* out_bn    = out_state + (size_t)BB * NN;   // B*N*D

    edge_kernel<<<EE / 4, 256, 0, stream>>>(x, eidx, weight, bias, sums_h, cnt);

    int node_threads = NN * 64;
    node_kernel<<<(node_threads + 255) / 256, 256, 0, stream>>>(
        sums_h, cnt, state_w, state_b, bn_gamma, bn_beta, out_state, out_bn);
}